// Round 1
// baseline (320.656 us; speedup 1.0000x reference)
//
#include <hip/hip_runtime.h>

// SIZE=65536 nodes, MAX_EDGES=16777216.
// out[i] = bias[i] + sum over edges e with dst[e]==i of x[src[e]]*w[e].
//
// R1: global fp32 atomics ~20.6 G/s -> LDS histograms.
// R2: batched guarded gathers / ds_adds.
// R3: ~135us constant harness overhead; hist is the only real cost.
//     RANGES 4->2 via 128KB dynamic LDS.
// R4: rocprof showed hist latency-bound (HBM 21%, VALU 6%, VGPR=20!):
//     compiler collapsed the batch into a serial per-edge dependence chain.
//     Fix: explicit 3-stage software pipeline in named registers
//     (stream k+2 || gather k+1 || atomics k), UNconditional gathers
//     (x[s] always valid; only ds_add guarded) to kill the divergent
//     branches that fragmented live ranges, and XCD-pairing block swizzle
//     so the two blocks sharing a chunk share an L2.

#define NNODES  65536
#define NEDGES  16777216
#define RANGES  2
#define BINS    (NNODES / RANGES)   // 32768 bins -> 128 KB dynamic LDS
#define THREADS 1024
#define NCOPIES 128                 // private output copies in ws (32 MB)
#define GROUPS  16
#define CPG     (NCOPIES / GROUPS)  // 8 copies per reduce group

struct E8 { int4 sa, sb, da, db; float4 wa, wb; };
struct V8 { float v0, v1, v2, v3, v4, v5, v6, v7; };

__device__ __forceinline__ E8 load8(const int4* __restrict__ s4,
                                    const int4* __restrict__ d4,
                                    const float4* __restrict__ w4, int g) {
    E8 e;
    e.sa = s4[2 * g];  e.sb = s4[2 * g + 1];
    e.da = d4[2 * g];  e.db = d4[2 * g + 1];
    e.wa = w4[2 * g];  e.wb = w4[2 * g + 1];
    return e;
}

// Unconditional gathers: x[s] is always a valid address regardless of range,
// so no divergent branch here -- all 8 loads issue back-to-back.
__device__ __forceinline__ V8 gather8(const float* __restrict__ x, const E8& e) {
    V8 r;
    r.v0 = x[e.sa.x] * e.wa.x;
    r.v1 = x[e.sa.y] * e.wa.y;
    r.v2 = x[e.sa.z] * e.wa.z;
    r.v3 = x[e.sa.w] * e.wa.w;
    r.v4 = x[e.sb.x] * e.wb.x;
    r.v5 = x[e.sb.y] * e.wb.y;
    r.v6 = x[e.sb.z] * e.wb.z;
    r.v7 = x[e.sb.w] * e.wb.w;
    return r;
}

__device__ __forceinline__ void atom8(float* h, int lo, const E8& e, const V8& r) {
    unsigned b0 = (unsigned)(e.da.x - lo);
    unsigned b1 = (unsigned)(e.da.y - lo);
    unsigned b2 = (unsigned)(e.da.z - lo);
    unsigned b3 = (unsigned)(e.da.w - lo);
    unsigned b4 = (unsigned)(e.db.x - lo);
    unsigned b5 = (unsigned)(e.db.y - lo);
    unsigned b6 = (unsigned)(e.db.z - lo);
    unsigned b7 = (unsigned)(e.db.w - lo);
    if (b0 < (unsigned)BINS) atomicAdd(&h[b0], r.v0);
    if (b1 < (unsigned)BINS) atomicAdd(&h[b1], r.v1);
    if (b2 < (unsigned)BINS) atomicAdd(&h[b2], r.v2);
    if (b3 < (unsigned)BINS) atomicAdd(&h[b3], r.v3);
    if (b4 < (unsigned)BINS) atomicAdd(&h[b4], r.v4);
    if (b5 < (unsigned)BINS) atomicAdd(&h[b5], r.v5);
    if (b6 < (unsigned)BINS) atomicAdd(&h[b6], r.v6);
    if (b7 < (unsigned)BINS) atomicAdd(&h[b7], r.v7);
}

// ---------------- Stage 1: LDS histograms ----------------
// Block swizzle: range r = bit3, chunk c = remaining bits. Blocks b and b^8
// share a chunk AND (with round-robin XCD placement, b%8) share an XCD ->
// the duplicate edge-stream read is an L2 hit, not L3.
__global__ __launch_bounds__(THREADS, 4) void hist_kernel(
    const float* __restrict__ x,
    const float* __restrict__ w,
    const int*   __restrict__ src,
    const int*   __restrict__ dst,
    float*       __restrict__ ws,
    int B)
{
    extern __shared__ float h[];   // BINS floats = 128 KB

    const int b  = blockIdx.x;
    const int r  = (b >> 3) & (RANGES - 1);
    const int c  = (b & 7) | ((b >> 4) << 3);
    const int lo = r * BINS;

    for (int i = threadIdx.x; i < BINS; i += THREADS) h[i] = 0.0f;
    __syncthreads();

    const int4*   src4 = (const int4*)src;
    const int4*   dst4 = (const int4*)dst;
    const float4* wgt4 = (const float4*)w;

    const int n8     = NEDGES / 8;
    const int stride = B * THREADS;
    const int g0     = c * THREADS + (int)threadIdx.x;   // < stride always

    if ((n8 % stride) == 0 && (n8 / stride) >= 2) {
        // -------- 3-stage software pipeline (uniform trip count) --------
        const int niter = n8 / stride;                   // 16 when B=128
        E8 e0 = load8(src4, dst4, wgt4, g0);             // stream grp 0
        V8 r0 = gather8(x, e0);                          // gathers grp 0
        E8 e1 = load8(src4, dst4, wgt4, g0 + stride);    // stream grp 1
        int g2 = g0 + 2 * stride;
        for (int it = 0; it < niter - 2; ++it, g2 += stride) {
            E8 e2 = load8(src4, dst4, wgt4, g2);         // stream grp k+2
            V8 r1 = gather8(x, e1);                      // gathers grp k+1
            atom8(h, lo, e0, r0);                        // atomics grp k
            e0 = e1; r0 = r1; e1 = e2;
        }
        V8 r1 = gather8(x, e1);                          // epilogue
        atom8(h, lo, e0, r0);
        atom8(h, lo, e1, r1);
    } else {
        // -------- generic guarded loop (B != power-path) --------
        for (int g = g0; g < n8; g += stride) {
            E8 e = load8(src4, dst4, wgt4, g);
            V8 v = gather8(x, e);
            atom8(h, lo, e, v);
        }
    }

    __syncthreads();

    float* outc = ws + (size_t)c * NNODES + lo;
    for (int i = threadIdx.x; i < BINS; i += THREADS) outc[i] = h[i];
}

// ---------------- Stage 2a: tree reduce 128 -> 16 (in-place) ----------------
__global__ __launch_bounds__(256) void reduceA_kernel(float* __restrict__ ws)
{
    const int NB = NNODES / (256 * 4);          // 64 slice-blocks per group
    int g  = blockIdx.x / NB;
    int jb = blockIdx.x % NB;
    int i4 = jb * 256 + (int)threadIdx.x;       // float4 index in [0, 16384)

    float4* w4 = (float4*)ws;
    const int stride4 = NNODES / 4;

    float4 acc = w4[(size_t)(g * CPG) * stride4 + i4];
    #pragma unroll
    for (int cc = 1; cc < CPG; ++cc) {
        float4 t = w4[(size_t)(g * CPG + cc) * stride4 + i4];
        acc.x += t.x; acc.y += t.y; acc.z += t.z; acc.w += t.w;
    }
    w4[(size_t)(g * CPG) * stride4 + i4] = acc;
}

// ---------------- Stage 2b: 16 partials + bias -> out ----------------
__global__ __launch_bounds__(256) void reduceB_kernel(
    const float* __restrict__ ws,
    const float* __restrict__ bias,
    float*       __restrict__ out)
{
    int i4 = blockIdx.x * 256 + (int)threadIdx.x;  // float4 index
    const float4* w4 = (const float4*)ws;
    const int stride4 = NNODES / 4;

    float4 acc = ((const float4*)bias)[i4];
    #pragma unroll
    for (int g = 0; g < GROUPS; ++g) {
        float4 t = w4[(size_t)(g * CPG) * stride4 + i4];
        acc.x += t.x; acc.y += t.y; acc.z += t.z; acc.w += t.w;
    }
    ((float4*)out)[i4] = acc;
}

// ---------------- Generic fallback reduce (B != NCOPIES) ----------------
__global__ __launch_bounds__(256) void reduce_generic_kernel(
    const float* __restrict__ ws,
    const float* __restrict__ bias,
    float*       __restrict__ out,
    int B)
{
    int i = blockIdx.x * 256 + (int)threadIdx.x;
    float acc = bias[i];
    for (int cc = 0; cc < B; ++cc) acc += ws[(size_t)cc * NNODES + i];
    out[i] = acc;
}

// ---------------- Fallback: global atomics (tiny ws) ----------------
__global__ __launch_bounds__(256) void init_out_kernel(
    const float* __restrict__ bias, float* __restrict__ out)
{
    int i = blockIdx.x * blockDim.x + threadIdx.x;
    if (i < NNODES) out[i] = bias[i];
}

__global__ __launch_bounds__(256) void edge_atomic_kernel(
    const float* __restrict__ x, const float* __restrict__ w,
    const int* __restrict__ src, const int* __restrict__ dst,
    float* __restrict__ out)
{
    const int n4 = NEDGES / 4;
    int tid = blockIdx.x * blockDim.x + threadIdx.x;
    int stride = gridDim.x * blockDim.x;
    for (int i = tid; i < n4; i += stride) {
        int4 s = ((const int4*)src)[i];
        int4 d = ((const int4*)dst)[i];
        float4 ww = ((const float4*)w)[i];
        atomicAdd(&out[d.x], x[s.x] * ww.x);
        atomicAdd(&out[d.y], x[s.y] * ww.y);
        atomicAdd(&out[d.z], x[s.z] * ww.z);
        atomicAdd(&out[d.w], x[s.w] * ww.w);
    }
}

extern "C" void kernel_launch(void* const* d_in, const int* in_sizes, int n_in,
                              void* d_out, int out_size, void* d_ws, size_t ws_size,
                              hipStream_t stream) {
    const float* x    = (const float*)d_in[0];
    const float* w    = (const float*)d_in[1];
    const float* bias = (const float*)d_in[2];
    const int*   src  = (const int*)d_in[3];
    const int*   dst  = (const int*)d_in[4];
    float* out = (float*)d_out;
    float* ws  = (float*)d_ws;

    size_t copies = ws_size / ((size_t)NNODES * sizeof(float));
    int B = (int)(copies < NCOPIES ? copies : NCOPIES);

    if (B >= 1) {
        // 256 blocks (B=128 x 2 ranges), 1 block/CU, 128 KB dynamic LDS.
        hist_kernel<<<B * RANGES, THREADS, BINS * sizeof(float), stream>>>(
            x, w, src, dst, ws, B);
        if (B == NCOPIES) {
            reduceA_kernel<<<GROUPS * (NNODES / 1024), 256, 0, stream>>>(ws);
            reduceB_kernel<<<NNODES / 1024, 256, 0, stream>>>(ws, bias, out);
        } else {
            reduce_generic_kernel<<<NNODES / 256, 256, 0, stream>>>(ws, bias, out, B);
        }
    } else {
        init_out_kernel<<<NNODES / 256, 256, 0, stream>>>(bias, out);
        edge_atomic_kernel<<<4096, 256, 0, stream>>>(x, w, src, dst, out);
    }
}

// Round 2
// 292.180 us; speedup vs baseline: 1.0975x; 1.0975x over previous
//
#include <hip/hip_runtime.h>

// SIZE=65536 nodes, MAX_EDGES=16777216.
// out[i] = bias[i] + sum over edges e with dst[e]==i of x[src[e]]*w[e].
//
// R1: global fp32 atomics ~20.6 G/s -> LDS histograms.
// R2: batched guarded gathers / ds_adds.
// R3: ~135us constant harness overhead; hist is the only real cost.
// R4: software-pipeline + UNconditional gathers REGRESSED (141->190us):
//     doubling gathers 16M->32M added ~50us => gathers are the dominant
//     latency component; ILP route fights the register allocator.
//     KEPT: XCD-pairing swizzle (FETCH 198->101MB proves chunk-siblings
//     share L2).
// R5: attack TLP instead. Occupancy was LDS-capped at 16 waves/CU
//     (1 block x 128KB). RANGES 2->4: 64KB LDS -> 2 blocks/CU -> 32
//     waves/CU (100%). Extra 2x stream scan is L2-cheap via the swizzle
//     (1.5MB chunk, 4 co-located siblings); gathers stay guarded (16M).
//     launch_bounds(1024,8) forces VGPR<=64 so 2 blocks/CU fit.

#define NNODES  65536
#define NEDGES  16777216
#define RANGES  4
#define BINS    (NNODES / RANGES)   // 16384 bins -> 64 KB dynamic LDS
#define THREADS 1024
#define NCOPIES 128                 // private output copies in ws (32 MB)
#define GROUPS  16
#define CPG     (NCOPIES / GROUPS)  // 8 copies per reduce group

// ---------------- Stage 1: LDS histograms ----------------
// Swizzle (B==128, grid=512): r = b[3:5), c = b[0:3) | b[5:9)<<3.
// The 4 blocks sharing chunk c differ only in bits [3:5) -> same b%8 ->
// same XCD under round-robin placement -> chunk re-reads hit that XCD's L2.
__global__ __launch_bounds__(THREADS, 8) void hist_kernel(
    const float* __restrict__ x,
    const float* __restrict__ w,
    const int*   __restrict__ src,
    const int*   __restrict__ dst,
    float*       __restrict__ ws,
    int B)
{
    extern __shared__ float h[];   // BINS floats = 64 KB

    const int b = blockIdx.x;
    int r, c;
    if (B == NCOPIES) {
        r = (b >> 3) & (RANGES - 1);
        c = (b & 7) | ((b >> 5) << 3);
    } else {
        r = b & (RANGES - 1);
        c = b >> 2;
    }
    const int lo = r * BINS;

    for (int i = threadIdx.x; i < BINS; i += THREADS) h[i] = 0.0f;
    __syncthreads();

    const int4*   src4 = (const int4*)src;
    const int4*   dst4 = (const int4*)dst;
    const float4* wgt4 = (const float4*)w;

    const int n8 = NEDGES / 8;
    for (int g = c * THREADS + (int)threadIdx.x; g < n8; g += B * THREADS) {
        int4   sa = src4[2 * g], sb = src4[2 * g + 1];
        int4   da = dst4[2 * g], db = dst4[2 * g + 1];
        float4 wa = wgt4[2 * g], wb = wgt4[2 * g + 1];

        int      s[8]  = { sa.x, sa.y, sa.z, sa.w, sb.x, sb.y, sb.z, sb.w };
        unsigned bin[8] = {
            (unsigned)(da.x - lo), (unsigned)(da.y - lo),
            (unsigned)(da.z - lo), (unsigned)(da.w - lo),
            (unsigned)(db.x - lo), (unsigned)(db.y - lo),
            (unsigned)(db.z - lo), (unsigned)(db.w - lo) };
        float    wv[8] = { wa.x, wa.y, wa.z, wa.w, wb.x, wb.y, wb.z, wb.w };

        // Pass 1: guarded gathers only (group under one vmcnt wait).
        float v[8];
        #pragma unroll
        for (int k = 0; k < 8; ++k) {
            v[k] = 0.0f;
            if (bin[k] < (unsigned)BINS) v[k] = x[s[k]] * wv[k];
        }
        // Pass 2: guarded LDS atomics (fire-and-forget).
        #pragma unroll
        for (int k = 0; k < 8; ++k) {
            if (bin[k] < (unsigned)BINS) atomicAdd(&h[bin[k]], v[k]);
        }
    }
    __syncthreads();

    float* outc = ws + (size_t)c * NNODES + lo;
    for (int i = threadIdx.x; i < BINS; i += THREADS) outc[i] = h[i];
}

// ---------------- Stage 2a: tree reduce 128 -> 16 (in-place) ----------------
__global__ __launch_bounds__(256) void reduceA_kernel(float* __restrict__ ws)
{
    const int NB = NNODES / (256 * 4);          // 64 slice-blocks per group
    int g  = blockIdx.x / NB;
    int jb = blockIdx.x % NB;
    int i4 = jb * 256 + (int)threadIdx.x;       // float4 index in [0, 16384)

    float4* w4 = (float4*)ws;
    const int stride4 = NNODES / 4;

    float4 acc = w4[(size_t)(g * CPG) * stride4 + i4];
    #pragma unroll
    for (int cc = 1; cc < CPG; ++cc) {
        float4 t = w4[(size_t)(g * CPG + cc) * stride4 + i4];
        acc.x += t.x; acc.y += t.y; acc.z += t.z; acc.w += t.w;
    }
    w4[(size_t)(g * CPG) * stride4 + i4] = acc;
}

// ---------------- Stage 2b: 16 partials + bias -> out ----------------
__global__ __launch_bounds__(256) void reduceB_kernel(
    const float* __restrict__ ws,
    const float* __restrict__ bias,
    float*       __restrict__ out)
{
    int i4 = blockIdx.x * 256 + (int)threadIdx.x;  // float4 index
    const float4* w4 = (const float4*)ws;
    const int stride4 = NNODES / 4;

    float4 acc = ((const float4*)bias)[i4];
    #pragma unroll
    for (int g = 0; g < GROUPS; ++g) {
        float4 t = w4[(size_t)(g * CPG) * stride4 + i4];
        acc.x += t.x; acc.y += t.y; acc.z += t.z; acc.w += t.w;
    }
    ((float4*)out)[i4] = acc;
}

// ---------------- Generic fallback reduce (B != NCOPIES) ----------------
__global__ __launch_bounds__(256) void reduce_generic_kernel(
    const float* __restrict__ ws,
    const float* __restrict__ bias,
    float*       __restrict__ out,
    int B)
{
    int i = blockIdx.x * 256 + (int)threadIdx.x;
    float acc = bias[i];
    for (int cc = 0; cc < B; ++cc) acc += ws[(size_t)cc * NNODES + i];
    out[i] = acc;
}

// ---------------- Fallback: global atomics (tiny ws) ----------------
__global__ __launch_bounds__(256) void init_out_kernel(
    const float* __restrict__ bias, float* __restrict__ out)
{
    int i = blockIdx.x * blockDim.x + threadIdx.x;
    if (i < NNODES) out[i] = bias[i];
}

__global__ __launch_bounds__(256) void edge_atomic_kernel(
    const float* __restrict__ x, const float* __restrict__ w,
    const int* __restrict__ src, const int* __restrict__ dst,
    float* __restrict__ out)
{
    const int n4 = NEDGES / 4;
    int tid = blockIdx.x * blockDim.x + threadIdx.x;
    int stride = gridDim.x * blockDim.x;
    for (int i = tid; i < n4; i += stride) {
        int4 s = ((const int4*)src)[i];
        int4 d = ((const int4*)dst)[i];
        float4 ww = ((const float4*)w)[i];
        atomicAdd(&out[d.x], x[s.x] * ww.x);
        atomicAdd(&out[d.y], x[s.y] * ww.y);
        atomicAdd(&out[d.z], x[s.z] * ww.z);
        atomicAdd(&out[d.w], x[s.w] * ww.w);
    }
}

extern "C" void kernel_launch(void* const* d_in, const int* in_sizes, int n_in,
                              void* d_out, int out_size, void* d_ws, size_t ws_size,
                              hipStream_t stream) {
    const float* x    = (const float*)d_in[0];
    const float* w    = (const float*)d_in[1];
    const float* bias = (const float*)d_in[2];
    const int*   src  = (const int*)d_in[3];
    const int*   dst  = (const int*)d_in[4];
    float* out = (float*)d_out;
    float* ws  = (float*)d_ws;

    size_t copies = ws_size / ((size_t)NNODES * sizeof(float));
    int B = (int)(copies < NCOPIES ? copies : NCOPIES);

    if (B >= 1) {
        // 512 blocks (B=128 x 4 ranges), 2 blocks/CU, 64 KB dynamic LDS.
        hist_kernel<<<B * RANGES, THREADS, BINS * sizeof(float), stream>>>(
            x, w, src, dst, ws, B);
        if (B == NCOPIES) {
            reduceA_kernel<<<GROUPS * (NNODES / 1024), 256, 0, stream>>>(ws);
            reduceB_kernel<<<NNODES / 1024, 256, 0, stream>>>(ws, bias, out);
        } else {
            reduce_generic_kernel<<<NNODES / 256, 256, 0, stream>>>(ws, bias, out, B);
        }
    } else {
        init_out_kernel<<<NNODES / 256, 256, 0, stream>>>(bias, out);
        edge_atomic_kernel<<<4096, 256, 0, stream>>>(x, w, src, dst, out);
    }
}

// Round 4
// 265.116 us; speedup vs baseline: 1.2095x; 1.1021x over previous
//
#include <hip/hip_runtime.h>

// SIZE=65536 nodes, MAX_EDGES=16777216.
// out[i] = bias[i] + sum over edges e with dst[e]==i of x[src[e]]*w[e].
//
// R1: global fp32 atomics ~20.6 G/s -> LDS histograms.
// R2: batched guarded gathers / ds_adds.
// R3: ~135us constant harness overhead; hist is the only real cost.
// R4: pipeline + UNconditional gathers regressed (141->190): doubling
//     gathers 16M->32M costs ~50us => gather term G~49us per 16M.
//     KEPT: XCD-pairing swizzle (FETCH 198->101MB: chunk-siblings share L2).
// R5: RANGES=4 for 2 blocks/CU: occupancy 42->80% worked, but 2x stream
//     scan ate the gain (141->156). Model: S~17us/scan, G~49us, O~58us
//     latency residual @16w. Best combo never measured!
// R6: RANGES=2 + XCD swizzle + guarded gathers + intra-iteration unroll x2:
//     issue 24 stream loads (2 groups), then 16 guarded gathers, then 16
//     ds_adds. One HBM stall covers 16 edges instead of 8 -> O should ~halve.
//     No cross-iteration register carry (that fought the allocator in R4).
// R7: R6 bench was an infra failure (container died twice); resubmitting
//     unchanged to get the measurement.

#define NNODES  65536
#define NEDGES  16777216
#define RANGES  2
#define BINS    (NNODES / RANGES)   // 32768 bins -> 128 KB dynamic LDS
#define THREADS 1024
#define NCOPIES 128                 // private output copies in ws (32 MB)
#define GROUPS  16
#define CPG     (NCOPIES / GROUPS)  // 8 copies per reduce group

// ---------------- Stage 1: LDS histograms ----------------
// Swizzle (B==128, grid=256): r = bit3, c = b[0:3) | b[4:8)<<3.
// The 2 blocks sharing chunk c differ only in bit 3 -> same b%8 -> same XCD
// under round-robin placement -> the duplicate chunk read is an L2 hit.
__global__ __launch_bounds__(THREADS, 4) void hist_kernel(
    const float* __restrict__ x,
    const float* __restrict__ w,
    const int*   __restrict__ src,
    const int*   __restrict__ dst,
    float*       __restrict__ ws,
    int B)
{
    extern __shared__ float h[];   // BINS floats = 128 KB

    const int b = blockIdx.x;
    int r, c;
    if (B == NCOPIES) {
        r = (b >> 3) & (RANGES - 1);
        c = (b & 7) | ((b >> 4) << 3);
    } else {
        r = b & (RANGES - 1);
        c = b >> 1;
    }
    const int lo = r * BINS;

    for (int i = threadIdx.x; i < BINS; i += THREADS) h[i] = 0.0f;
    __syncthreads();

    const int4*   src4 = (const int4*)src;
    const int4*   dst4 = (const int4*)dst;
    const float4* wgt4 = (const float4*)w;

    const int n8     = NEDGES / 8;
    const int stride = B * THREADS;
    int g = c * THREADS + (int)threadIdx.x;       // < stride always

    if ((n8 % (2 * stride)) == 0 && n8 >= 2 * stride) {
        // -------- fast path: 2 groups (16 edges) per outer iteration --------
        const int niter2 = n8 / (2 * stride);     // 8 when B=128
        for (int it = 0; it < niter2; ++it, g += 2 * stride) {
            const int ga = g;
            const int gb = g + stride;

            // All stream loads for both groups issued back-to-back.
            int4   sA0 = src4[2 * ga], sA1 = src4[2 * ga + 1];
            int4   sB0 = src4[2 * gb], sB1 = src4[2 * gb + 1];
            int4   dA0 = dst4[2 * ga], dA1 = dst4[2 * ga + 1];
            int4   dB0 = dst4[2 * gb], dB1 = dst4[2 * gb + 1];
            float4 wA0 = wgt4[2 * ga], wA1 = wgt4[2 * ga + 1];
            float4 wB0 = wgt4[2 * gb], wB1 = wgt4[2 * gb + 1];

            int s[16] = { sA0.x, sA0.y, sA0.z, sA0.w,
                          sA1.x, sA1.y, sA1.z, sA1.w,
                          sB0.x, sB0.y, sB0.z, sB0.w,
                          sB1.x, sB1.y, sB1.z, sB1.w };
            unsigned bin[16] = {
                (unsigned)(dA0.x - lo), (unsigned)(dA0.y - lo),
                (unsigned)(dA0.z - lo), (unsigned)(dA0.w - lo),
                (unsigned)(dA1.x - lo), (unsigned)(dA1.y - lo),
                (unsigned)(dA1.z - lo), (unsigned)(dA1.w - lo),
                (unsigned)(dB0.x - lo), (unsigned)(dB0.y - lo),
                (unsigned)(dB0.z - lo), (unsigned)(dB0.w - lo),
                (unsigned)(dB1.x - lo), (unsigned)(dB1.y - lo),
                (unsigned)(dB1.z - lo), (unsigned)(dB1.w - lo) };
            float wv[16] = { wA0.x, wA0.y, wA0.z, wA0.w,
                             wA1.x, wA1.y, wA1.z, wA1.w,
                             wB0.x, wB0.y, wB0.z, wB0.w,
                             wB1.x, wB1.y, wB1.z, wB1.w };

            // Pass 1: guarded gathers only (batched under few vmcnt waits).
            float v[16];
            #pragma unroll
            for (int k = 0; k < 16; ++k) {
                v[k] = 0.0f;
                if (bin[k] < (unsigned)BINS) v[k] = x[s[k]] * wv[k];
            }
            // Pass 2: guarded LDS atomics (fire-and-forget).
            #pragma unroll
            for (int k = 0; k < 16; ++k) {
                if (bin[k] < (unsigned)BINS) atomicAdd(&h[bin[k]], v[k]);
            }
        }
    } else {
        // -------- generic guarded loop --------
        for (; g < n8; g += stride) {
            int4   sa = src4[2 * g], sb = src4[2 * g + 1];
            int4   da = dst4[2 * g], db = dst4[2 * g + 1];
            float4 wa = wgt4[2 * g], wb = wgt4[2 * g + 1];

            int      s[8]  = { sa.x, sa.y, sa.z, sa.w, sb.x, sb.y, sb.z, sb.w };
            unsigned bin[8] = {
                (unsigned)(da.x - lo), (unsigned)(da.y - lo),
                (unsigned)(da.z - lo), (unsigned)(da.w - lo),
                (unsigned)(db.x - lo), (unsigned)(db.y - lo),
                (unsigned)(db.z - lo), (unsigned)(db.w - lo) };
            float    wv[8] = { wa.x, wa.y, wa.z, wa.w, wb.x, wb.y, wb.z, wb.w };

            float v[8];
            #pragma unroll
            for (int k = 0; k < 8; ++k) {
                v[k] = 0.0f;
                if (bin[k] < (unsigned)BINS) v[k] = x[s[k]] * wv[k];
            }
            #pragma unroll
            for (int k = 0; k < 8; ++k) {
                if (bin[k] < (unsigned)BINS) atomicAdd(&h[bin[k]], v[k]);
            }
        }
    }
    __syncthreads();

    float* outc = ws + (size_t)c * NNODES + lo;
    for (int i = threadIdx.x; i < BINS; i += THREADS) outc[i] = h[i];
}

// ---------------- Stage 2a: tree reduce 128 -> 16 (in-place) ----------------
__global__ __launch_bounds__(256) void reduceA_kernel(float* __restrict__ ws)
{
    const int NB = NNODES / (256 * 4);          // 64 slice-blocks per group
    int g  = blockIdx.x / NB;
    int jb = blockIdx.x % NB;
    int i4 = jb * 256 + (int)threadIdx.x;       // float4 index in [0, 16384)

    float4* w4 = (float4*)ws;
    const int stride4 = NNODES / 4;

    float4 acc = w4[(size_t)(g * CPG) * stride4 + i4];
    #pragma unroll
    for (int cc = 1; cc < CPG; ++cc) {
        float4 t = w4[(size_t)(g * CPG + cc) * stride4 + i4];
        acc.x += t.x; acc.y += t.y; acc.z += t.z; acc.w += t.w;
    }
    w4[(size_t)(g * CPG) * stride4 + i4] = acc;
}

// ---------------- Stage 2b: 16 partials + bias -> out ----------------
__global__ __launch_bounds__(256) void reduceB_kernel(
    const float* __restrict__ ws,
    const float* __restrict__ bias,
    float*       __restrict__ out)
{
    int i4 = blockIdx.x * 256 + (int)threadIdx.x;  // float4 index
    const float4* w4 = (const float4*)ws;
    const int stride4 = NNODES / 4;

    float4 acc = ((const float4*)bias)[i4];
    #pragma unroll
    for (int g = 0; g < GROUPS; ++g) {
        float4 t = w4[(size_t)(g * CPG) * stride4 + i4];
        acc.x += t.x; acc.y += t.y; acc.z += t.z; acc.w += t.w;
    }
    ((float4*)out)[i4] = acc;
}

// ---------------- Generic fallback reduce (B != NCOPIES) ----------------
__global__ __launch_bounds__(256) void reduce_generic_kernel(
    const float* __restrict__ ws,
    const float* __restrict__ bias,
    float*       __restrict__ out,
    int B)
{
    int i = blockIdx.x * 256 + (int)threadIdx.x;
    float acc = bias[i];
    for (int cc = 0; cc < B; ++cc) acc += ws[(size_t)cc * NNODES + i];
    out[i] = acc;
}

// ---------------- Fallback: global atomics (tiny ws) ----------------
__global__ __launch_bounds__(256) void init_out_kernel(
    const float* __restrict__ bias, float* __restrict__ out)
{
    int i = blockIdx.x * blockDim.x + threadIdx.x;
    if (i < NNODES) out[i] = bias[i];
}

__global__ __launch_bounds__(256) void edge_atomic_kernel(
    const float* __restrict__ x, const float* __restrict__ w,
    const int* __restrict__ src, const int* __restrict__ dst,
    float* __restrict__ out)
{
    const int n4 = NEDGES / 4;
    int tid = blockIdx.x * blockDim.x + threadIdx.x;
    int stride = gridDim.x * blockDim.x;
    for (int i = tid; i < n4; i += stride) {
        int4 s = ((const int4*)src)[i];
        int4 d = ((const int4*)dst)[i];
        float4 ww = ((const float4*)w)[i];
        atomicAdd(&out[d.x], x[s.x] * ww.x);
        atomicAdd(&out[d.y], x[s.y] * ww.y);
        atomicAdd(&out[d.z], x[s.z] * ww.z);
        atomicAdd(&out[d.w], x[s.w] * ww.w);
    }
}

extern "C" void kernel_launch(void* const* d_in, const int* in_sizes, int n_in,
                              void* d_out, int out_size, void* d_ws, size_t ws_size,
                              hipStream_t stream) {
    const float* x    = (const float*)d_in[0];
    const float* w    = (const float*)d_in[1];
    const float* bias = (const float*)d_in[2];
    const int*   src  = (const int*)d_in[3];
    const int*   dst  = (const int*)d_in[4];
    float* out = (float*)d_out;
    float* ws  = (float*)d_ws;

    size_t copies = ws_size / ((size_t)NNODES * sizeof(float));
    int B = (int)(copies < NCOPIES ? copies : NCOPIES);

    if (B >= 1) {
        // 256 blocks (B=128 x 2 ranges), 1 block/CU, 128 KB dynamic LDS.
        hist_kernel<<<B * RANGES, THREADS, BINS * sizeof(float), stream>>>(
            x, w, src, dst, ws, B);
        if (B == NCOPIES) {
            reduceA_kernel<<<GROUPS * (NNODES / 1024), 256, 0, stream>>>(ws);
            reduceB_kernel<<<NNODES / 1024, 256, 0, stream>>>(ws, bias, out);
        } else {
            reduce_generic_kernel<<<NNODES / 256, 256, 0, stream>>>(ws, bias, out, B);
        }
    } else {
        init_out_kernel<<<NNODES / 256, 256, 0, stream>>>(bias, out);
        edge_atomic_kernel<<<4096, 256, 0, stream>>>(x, w, src, dst, out);
    }
}